// Round 1
// 906.051 us; speedup vs baseline: 1.0450x; 1.0450x over previous
//
#include <hip/hip_runtime.h>
#include <hip/hip_bf16.h>

// Problem constants
#define BB   16
#define LL   50
#define PP   49
#define TT   20
#define DD   512
#define HH   8
#define DHH  64
#define DFF  2048

#define BL     (BB*LL)          // 800
#define ROWS_I (BL*TT)          // 16000
#define ROWS_T (BL*PP)          // 39200
#define ROWS_A (ROWS_I+ROWS_T)  // 55200
#define OUT_I_ELEMS ((size_t)ROWS_I*DD)
#define CHUNK 19600             // tit branch processed in 2 chunks

// ws layout (bytes) — total 185,860,096 (< proven 240 MB)
//  R0 act/hid : [0, 80,281,600)            act bf16 (<=19600x2048); hid bf16 (55200x512) early
//  R1 out_bf16: [80,281,600, +56,524,800)
//  R2 f2 fp32 : [136,806,400, +40,140,800)
//  R3 weights : [176,947,200, +8,912,896)
#define R1_OFF 80281600ull
#define R2_OFF 136806400ull
#define R3_OFF 176947200ull

typedef __attribute__((ext_vector_type(8))) short bf16x8;
typedef __attribute__((ext_vector_type(4))) float f32x4;

__device__ __forceinline__ unsigned short f2bf(float f) {
    union { float f; unsigned int i; } w; w.f = f;
    unsigned int x = w.i;
    unsigned int r = (x + 0x7fffu + ((x >> 16) & 1u)) >> 16;
    return (unsigned short)r;
}
__device__ __forceinline__ float gelu_tanh_f(float x) {
    float c = 0.7978845608028654f * (x + 0.044715f * x * x * x);
    return 0.5f * x * (1.0f + tanhf(c));
}

// ---------------------------------------------------------------------------
// fp32 -> bf16 convert (n4 = n/4)
// ---------------------------------------------------------------------------
__global__ __launch_bounds__(256) void cvt_kernel(
    const float* __restrict__ s, unsigned short* __restrict__ d, int n4)
{
    int i = blockIdx.x * 256 + threadIdx.x;
    if (i < n4) {
        float4 v = ((const float4*)s)[i];
        ushort4 u;
        u.x = f2bf(v.x); u.y = f2bf(v.y); u.z = f2bf(v.z); u.w = f2bf(v.w);
        ((ushort4*)d)[i] = u;
    }
}

// ---------------------------------------------------------------------------
// Attention: one block per (bl, h). Writes pre-proj hid (bf16) into ws:
//   hid_img rows [0,16000), hid_tit rows [16000,55200)
//
// Vectorized rewrite (R1): float4 LDS reads + register blocking.
//   Phase 1 (S=QK^T): thread (p, tg) computes t = tg+5j, j<4; 5x ds_read_b128
//     per 16 FMAs. stit row stride 68 floats => the 5 broadcast groups land on
//     5 distinct bank groups (t*68 mod 32 = 4t mod 32, t=tg..tg+4 distinct).
//   Phase 3 (PV): lane = d (64 lanes = DH). Probability rows read as float4
//     broadcasts (pT[t][p..p+3]); simg/stit column reads are 2-way (free).
// ---------------------------------------------------------------------------
__global__ __launch_bounds__(256) void attn_kernel(
    const float* __restrict__ img, const float* __restrict__ title,
    const int* __restrict__ mask, const float* __restrict__ scale_img,
    const float* __restrict__ scale_tit, unsigned short* __restrict__ hid)
{
    const int blh = blockIdx.x;
    const int h  = blh & 7;
    const int bl = blh >> 3;
    const int tid = threadIdx.x;
    const int wave = tid >> 6;
    const int lane = tid & 63;

    __shared__ __align__(16) float simg[PP][68];   // stride 68 floats (272 B, 16B-aligned)
    __shared__ __align__(16) float stit[TT][68];
    __shared__ __align__(16) float S [PP][TT];
    __shared__ __align__(16) float pI[PP][TT];     // row stride 80 B (16B-aligned)
    __shared__ __align__(16) float pT[TT][52];     // row stride 208 B (16B-aligned)
    __shared__ int   msk[TT];

    const float* imgbase = img   + (size_t)bl * PP * DD + h * DHH;
    const float* titbase = title + (size_t)bl * TT * DD + h * DHH;

    // ---- Phase 0: stage inputs (float4) ----
    for (int i = tid; i < PP * 16; i += 256) {
        int p = i >> 4, d4 = i & 15;
        *(float4*)&simg[p][d4 * 4] = *(const float4*)(imgbase + (size_t)p * DD + d4 * 4);
    }
    for (int i = tid; i < TT * 16; i += 256) {
        int t = i >> 4, d4 = i & 15;
        *(float4*)&stit[t][d4 * 4] = *(const float4*)(titbase + (size_t)t * DD + d4 * 4);
    }
    if (tid < TT) msk[tid] = mask[bl * TT + tid];
    __syncthreads();

    // ---- Phase 1: S[p][t] = dot(simg[p], stit[t]) * 0.125 ----
    if (tid < PP * 5) {
        const int p  = tid / 5;
        const int tg = tid - p * 5;
        float a0 = 0.f, a1 = 0.f, a2 = 0.f, a3 = 0.f;
        #pragma unroll 4
        for (int d = 0; d < DHH; d += 4) {
            float4 a  = *(const float4*)&simg[p][d];
            float4 b0 = *(const float4*)&stit[tg     ][d];
            float4 b1 = *(const float4*)&stit[tg +  5][d];
            float4 b2 = *(const float4*)&stit[tg + 10][d];
            float4 b3 = *(const float4*)&stit[tg + 15][d];
            a0 += a.x*b0.x + a.y*b0.y + a.z*b0.z + a.w*b0.w;
            a1 += a.x*b1.x + a.y*b1.y + a.z*b1.z + a.w*b1.w;
            a2 += a.x*b2.x + a.y*b2.y + a.z*b2.z + a.w*b2.w;
            a3 += a.x*b3.x + a.y*b3.y + a.z*b3.z + a.w*b3.w;
        }
        S[p][tg     ] = a0 * 0.125f;
        S[p][tg +  5] = a1 * 0.125f;
        S[p][tg + 10] = a2 * 0.125f;
        S[p][tg + 15] = a3 * 0.125f;
    }
    __syncthreads();

    // ---- Phase 2: softmax (pI over t, pT over p) ----
    if (tid < PP) {
        const int p = tid;
        const float sc = scale_img[h * PP + p];
        float m = -1e30f;
        #pragma unroll
        for (int t = 0; t < TT; ++t) {
            float x = (msk[t] == 0) ? -1e9f : S[p][t] * sc;
            m = fmaxf(m, x);
        }
        float sum = 0.f;
        #pragma unroll
        for (int t = 0; t < TT; ++t) {
            float x = (msk[t] == 0) ? -1e9f : S[p][t] * sc;
            float e = __expf(x - m);
            pI[p][t] = e; sum += e;
        }
        float inv = 1.f / sum;
        #pragma unroll
        for (int t = 0; t < TT; ++t) pI[p][t] *= inv;
    }
    if (tid >= 64 && tid < 64 + TT) {
        const int t = tid - 64;
        const float sc = scale_tit[h * TT + t];
        const bool dead = (msk[t] == 0);
        float m = -1e30f;
        #pragma unroll
        for (int p = 0; p < PP; ++p) {
            float x = dead ? -1e9f : S[p][t] * sc;
            m = fmaxf(m, x);
        }
        float sum = 0.f;
        #pragma unroll
        for (int p = 0; p < PP; ++p) {
            float x = dead ? -1e9f : S[p][t] * sc;
            float e = __expf(x - m);
            pT[t][p] = e; sum += e;
        }
        float inv = 1.f / sum;
        #pragma unroll
        for (int p = 0; p < PP; ++p) pT[t][p] *= inv;
    }
    __syncthreads();

    // ---- Phase 3a: hid_img[t][d] = sum_p pT[t][p] * simg[p][d] ----
    // wave w owns t = w + 4j (j<5); lane = d.
    {
        float accA[5] = {0.f, 0.f, 0.f, 0.f, 0.f};
        #pragma unroll
        for (int p = 0; p < 48; p += 4) {
            float v0 = simg[p + 0][lane];
            float v1 = simg[p + 1][lane];
            float v2 = simg[p + 2][lane];
            float v3 = simg[p + 3][lane];
            #pragma unroll
            for (int j = 0; j < 5; ++j) {
                const int t = wave + j * 4;
                float4 w4 = *(const float4*)&pT[t][p];
                accA[j] += v0 * w4.x + v1 * w4.y + v2 * w4.z + v3 * w4.w;
            }
        }
        {   // p = 48 tail
            float v0 = simg[48][lane];
            #pragma unroll
            for (int j = 0; j < 5; ++j)
                accA[j] += v0 * pT[wave + j * 4][48];
        }
        #pragma unroll
        for (int j = 0; j < 5; ++j) {
            const int t = wave + j * 4;
            hid[(size_t)(bl * TT + t) * DD + h * DHH + lane] = f2bf(accA[j]);
        }
    }

    // ---- Phase 3b: hid_tit[p][d] = sum_t pI[p][t] * stit[t][d] ----
    // wave w owns p = w + 4j (j<13, guarded); lane = d.
    {
        float accB[13] = {0.f,0.f,0.f,0.f,0.f,0.f,0.f,0.f,0.f,0.f,0.f,0.f,0.f};
        #pragma unroll
        for (int t = 0; t < TT; t += 4) {
            float v0 = stit[t + 0][lane];
            float v1 = stit[t + 1][lane];
            float v2 = stit[t + 2][lane];
            float v3 = stit[t + 3][lane];
            #pragma unroll
            for (int j = 0; j < 13; ++j) {
                const int p = wave + j * 4;
                if (p < PP) {
                    float4 w4 = *(const float4*)&pI[p][t];
                    accB[j] += v0 * w4.x + v1 * w4.y + v2 * w4.z + v3 * w4.w;
                }
            }
        }
        #pragma unroll
        for (int j = 0; j < 13; ++j) {
            const int p = wave + j * 4;
            if (p < PP)
                hid[OUT_I_ELEMS + (size_t)(bl * PP + p) * DD + h * DHH + lane] = f2bf(accB[j]);
        }
    }
}

// ---------------------------------------------------------------------------
// MFMA GEMM: C[M,N] = A[M,K](bf16) @ Bw[N,K](bf16)^T + bias[N]
// 128x128 tile, BK=32, 256 thr = 4 waves (2x2 of 64x64), mfma_f32_16x16x32_bf16.
// global_load_lds width-16 staging; unpadded [row][32] LDS layout (lane-ordered).
// Row-tail: reads clamped, stores guarded. N, K multiples of 128/32.
// ---------------------------------------------------------------------------
template<bool GELU, bool F32OUT, bool BF16OUT>
__global__ __launch_bounds__(256) void gemm_mfma(
    const unsigned short* __restrict__ A, const unsigned short* __restrict__ Bw,
    const float* __restrict__ bias,
    float* __restrict__ Cf, unsigned short* __restrict__ Cb,
    int M, int N, int K)
{
    __shared__ unsigned short As[128 * 32];
    __shared__ unsigned short Bs[128 * 32];
    const int tid  = threadIdx.x;
    const int wave = tid >> 6;
    const int lane = tid & 63;
    const int row0 = blockIdx.y * 128;
    const int col0 = blockIdx.x * 128;
    const int m_off = (wave >> 1) * 64;
    const int n_off = (wave & 1) * 64;
    const int lane_m = lane & 15;
    const int lane_k = (lane >> 4) * 8;

    f32x4 acc[4][4] = {};

    for (int k0 = 0; k0 < K; k0 += 32) {
        #pragma unroll
        for (int q = 0; q < 2; ++q) {
            const int li = q * 256 + tid;
            int gr = row0 + (li >> 2);
            if (gr >= M) gr = M - 1;                     // clamp (store-guarded later)
            const unsigned short* gp = A + (size_t)gr * K + k0 + (li & 3) * 8;
            __builtin_amdgcn_global_load_lds(
                (const __attribute__((address_space(1))) unsigned int*)gp,
                (__attribute__((address_space(3))) unsigned int*)&As[li * 8], 16, 0, 0);
        }
        #pragma unroll
        for (int q = 0; q < 2; ++q) {
            const int li = q * 256 + tid;
            const unsigned short* gp = Bw + (size_t)(col0 + (li >> 2)) * K + k0 + (li & 3) * 8;
            __builtin_amdgcn_global_load_lds(
                (const __attribute__((address_space(1))) unsigned int*)gp,
                (__attribute__((address_space(3))) unsigned int*)&Bs[li * 8], 16, 0, 0);
        }
        __syncthreads();

        bf16x8 af[4], bf[4];
        #pragma unroll
        for (int i = 0; i < 4; ++i) {
            af[i] = *(const bf16x8*)&As[(m_off + i * 16 + lane_m) * 32 + lane_k];
            bf[i] = *(const bf16x8*)&Bs[(n_off + i * 16 + lane_m) * 32 + lane_k];
        }
        #pragma unroll
        for (int i = 0; i < 4; ++i)
            #pragma unroll
            for (int j = 0; j < 4; ++j)
                acc[i][j] = __builtin_amdgcn_mfma_f32_16x16x32_bf16(af[i], bf[j], acc[i][j], 0, 0, 0);
        __syncthreads();
    }

    // Epilogue. C/D layout: col = lane&15, row = (lane>>4)*4 + reg
    #pragma unroll
    for (int i = 0; i < 4; ++i) {
        #pragma unroll
        for (int r = 0; r < 4; ++r) {
            const int row = row0 + m_off + i * 16 + (lane >> 4) * 4 + r;
            if (row < M) {
                #pragma unroll
                for (int j = 0; j < 4; ++j) {
                    const int col = col0 + n_off + j * 16 + lane_m;
                    float v = acc[i][j][r] + bias[col];
                    if (GELU) v = gelu_tanh_f(v);
                    if (F32OUT)  Cf[(size_t)row * N + col] = v;
                    if (BF16OUT) Cb[(size_t)row * N + col] = f2bf(v);
                }
            }
        }
    }
}

// ---------------------------------------------------------------------------
// Residual + LayerNorm (ddof=1): out[row] += a*(x-mean)/(std+eps)+b
// ---------------------------------------------------------------------------
__global__ __launch_bounds__(256) void ln_res_kernel(
    const float* __restrict__ f2, float* __restrict__ out,
    const float* __restrict__ a, const float* __restrict__ b, int M)
{
    const int wave = threadIdx.x >> 6;
    const int lane = threadIdx.x & 63;
    const int row = blockIdx.x * 4 + wave;
    if (row >= M) return;
    const float* x = f2 + (size_t)row * DD;
    float* o = out + (size_t)row * DD;

    float xs[8];
    float s1 = 0.f, s2 = 0.f;
    #pragma unroll
    for (int i = 0; i < 8; ++i) {
        float v = x[lane + i * 64];
        xs[i] = v; s1 += v; s2 += v * v;
    }
    #pragma unroll
    for (int off = 32; off > 0; off >>= 1) {
        s1 += __shfl_xor(s1, off, 64);
        s2 += __shfl_xor(s2, off, 64);
    }
    const float mean = s1 * (1.f / 512.f);
    float var = (s2 - 512.f * mean * mean) * (1.f / 511.f);
    var = fmaxf(var, 0.f);
    const float rinv = 1.f / (sqrtf(var) + 1e-6f);
    #pragma unroll
    for (int i = 0; i < 8; ++i) {
        const int d = lane + i * 64;
        o[d] = o[d] + a[d] * (xs[i] - mean) * rinv + b[d];
    }
}

// ---------------------------------------------------------------------------
extern "C" void kernel_launch(void* const* d_in, const int* in_sizes, int n_in,
                              void* d_out, int out_size, void* d_ws, size_t ws_size,
                              hipStream_t stream) {
    const float* img       = (const float*)d_in[0];
    const float* title     = (const float*)d_in[1];
    const int*   mask      = (const int*)  d_in[2];
    const float* scale_img = (const float*)d_in[3];
    const float* scale_tit = (const float*)d_in[4];
    const float* w_proj    = (const float*)d_in[5];
    const float* b_proj    = (const float*)d_in[6];
    const float* w1_img    = (const float*)d_in[7];
    const float* b1_img    = (const float*)d_in[8];
    const float* w2_img    = (const float*)d_in[9];
    const float* b2_img    = (const float*)d_in[10];
    const float* w1_tit    = (const float*)d_in[11];
    const float* b1_tit    = (const float*)d_in[12];
    const float* w2_tit    = (const float*)d_in[13];
    const float* b2_tit    = (const float*)d_in[14];
    const float* ln_a_img  = (const float*)d_in[15];
    const float* ln_b_img  = (const float*)d_in[16];
    const float* ln_a_tit  = (const float*)d_in[17];
    const float* ln_b_tit  = (const float*)d_in[18];

    float* out = (float*)d_out;
    unsigned short* hid_bf = (unsigned short*)d_ws;                       // R0 (early)
    unsigned short* act    = (unsigned short*)d_ws;                       // R0 (late)
    unsigned short* out_bf = (unsigned short*)((char*)d_ws + R1_OFF);     // R1
    float*          f2     = (float*)((char*)d_ws + R2_OFF);              // R2
    unsigned short* wp_bf  = (unsigned short*)((char*)d_ws + R3_OFF);     // R3
    unsigned short* w1i_bf = wp_bf  + 262144;
    unsigned short* w2i_bf = w1i_bf + 1048576;
    unsigned short* w1t_bf = w2i_bf + 1048576;
    unsigned short* w2t_bf = w1t_bf + 1048576;

    // 0) weights -> bf16
    cvt_kernel<<<(262144/4 + 255)/256, 256, 0, stream>>>(w_proj, wp_bf, 262144/4);
    cvt_kernel<<<(1048576/4 + 255)/256, 256, 0, stream>>>(w1_img, w1i_bf, 1048576/4);
    cvt_kernel<<<(1048576/4 + 255)/256, 256, 0, stream>>>(w2_img, w2i_bf, 1048576/4);
    cvt_kernel<<<(1048576/4 + 255)/256, 256, 0, stream>>>(w1_tit, w1t_bf, 1048576/4);
    cvt_kernel<<<(1048576/4 + 255)/256, 256, 0, stream>>>(w2_tit, w2t_bf, 1048576/4);

    // 1) attention -> hid_bf (bf16)
    attn_kernel<<<BL * HH, 256, 0, stream>>>(img, title, mask, scale_img, scale_tit, hid_bf);

    // 2) proj over all 55200 rows: fp32 -> d_out, bf16 copy -> out_bf
    gemm_mfma<false, true, true><<<dim3(DD/128, (ROWS_A + 127)/128), 256, 0, stream>>>(
        hid_bf, wp_bf, b_proj, out, out_bf, ROWS_A, DD, DD);

    // 3) img branch (16000 rows, one chunk)
    gemm_mfma<true, false, true><<<dim3(DFF/128, (ROWS_I + 127)/128), 256, 0, stream>>>(
        out_bf, w1i_bf, b1_img, nullptr, act, ROWS_I, DFF, DD);
    gemm_mfma<false, true, false><<<dim3(DD/128, (ROWS_I + 127)/128), 256, 0, stream>>>(
        act, w2i_bf, b2_img, f2, nullptr, ROWS_I, DD, DFF);
    ln_res_kernel<<<(ROWS_I + 3)/4, 256, 0, stream>>>(f2, out, ln_a_img, ln_b_img, ROWS_I);

    // 4) tit branch (39200 rows, two chunks of 19600)
    for (int c = 0; c < 2; ++c) {
        const unsigned short* a1 = out_bf + (size_t)(ROWS_I + c * CHUNK) * DD;
        float* o1 = out + OUT_I_ELEMS + (size_t)c * CHUNK * DD;
        gemm_mfma<true, false, true><<<dim3(DFF/128, (CHUNK + 127)/128), 256, 0, stream>>>(
            a1, w1t_bf, b1_tit, nullptr, act, CHUNK, DFF, DD);
        gemm_mfma<false, true, false><<<dim3(DD/128, (CHUNK + 127)/128), 256, 0, stream>>>(
            act, w2t_bf, b2_tit, f2, nullptr, CHUNK, DD, DFF);
        ln_res_kernel<<<(CHUNK + 3)/4, 256, 0, stream>>>(f2, o1, ln_a_tit, ln_b_tit, CHUNK);
    }
}

// Round 2
// 828.653 us; speedup vs baseline: 1.1426x; 1.0934x over previous
//
#include <hip/hip_runtime.h>
#include <hip/hip_bf16.h>

// Problem constants
#define BB   16
#define LL   50
#define PP   49
#define TT   20
#define DD   512
#define HH   8
#define DHH  64
#define DFF  2048

#define BL     (BB*LL)          // 800
#define ROWS_I (BL*TT)          // 16000
#define ROWS_T (BL*PP)          // 39200
#define ROWS_A (ROWS_I+ROWS_T)  // 55200
#define OUT_I_ELEMS ((size_t)ROWS_I*DD)
#define CHUNK 19600             // tit branch processed in 2 chunks

// ws layout (bytes) — total 185,860,096 (< proven 240 MB)
#define R1_OFF 80281600ull
#define R2_OFF 136806400ull
#define R3_OFF 176947200ull

typedef __attribute__((ext_vector_type(8))) short bf16x8;
typedef __attribute__((ext_vector_type(4))) float f32x4;

__device__ __forceinline__ unsigned short f2bf(float f) {
    union { float f; unsigned int i; } w; w.f = f;
    unsigned int x = w.i;
    unsigned int r = (x + 0x7fffu + ((x >> 16) & 1u)) >> 16;
    return (unsigned short)r;
}
// gelu_tanh(x) == x * sigmoid(2c), c = 0.79788456(x + 0.044715 x^3). One v_exp.
__device__ __forceinline__ float gelu_fast(float x) {
    float c2 = 1.5957691216057308f * (x + 0.044715f * x * x * x);
    return x / (1.0f + __expf(-c2));
}

// ---------------------------------------------------------------------------
// fp32 -> bf16 convert (n4 = n/4)
// ---------------------------------------------------------------------------
__global__ __launch_bounds__(256) void cvt_kernel(
    const float* __restrict__ s, unsigned short* __restrict__ d, int n4)
{
    int i = blockIdx.x * 256 + threadIdx.x;
    if (i < n4) {
        float4 v = ((const float4*)s)[i];
        ushort4 u;
        u.x = f2bf(v.x); u.y = f2bf(v.y); u.z = f2bf(v.z); u.w = f2bf(v.w);
        ((ushort4*)d)[i] = u;
    }
}

// ---------------------------------------------------------------------------
// Attention: one block per (bl, h). (unchanged from R1)
// ---------------------------------------------------------------------------
__global__ __launch_bounds__(256) void attn_kernel(
    const float* __restrict__ img, const float* __restrict__ title,
    const int* __restrict__ mask, const float* __restrict__ scale_img,
    const float* __restrict__ scale_tit, unsigned short* __restrict__ hid)
{
    const int blh = blockIdx.x;
    const int h  = blh & 7;
    const int bl = blh >> 3;
    const int tid = threadIdx.x;
    const int wave = tid >> 6;
    const int lane = tid & 63;

    __shared__ __align__(16) float simg[PP][68];
    __shared__ __align__(16) float stit[TT][68];
    __shared__ __align__(16) float S [PP][TT];
    __shared__ __align__(16) float pI[PP][TT];
    __shared__ __align__(16) float pT[TT][52];
    __shared__ int   msk[TT];

    const float* imgbase = img   + (size_t)bl * PP * DD + h * DHH;
    const float* titbase = title + (size_t)bl * TT * DD + h * DHH;

    for (int i = tid; i < PP * 16; i += 256) {
        int p = i >> 4, d4 = i & 15;
        *(float4*)&simg[p][d4 * 4] = *(const float4*)(imgbase + (size_t)p * DD + d4 * 4);
    }
    for (int i = tid; i < TT * 16; i += 256) {
        int t = i >> 4, d4 = i & 15;
        *(float4*)&stit[t][d4 * 4] = *(const float4*)(titbase + (size_t)t * DD + d4 * 4);
    }
    if (tid < TT) msk[tid] = mask[bl * TT + tid];
    __syncthreads();

    if (tid < PP * 5) {
        const int p  = tid / 5;
        const int tg = tid - p * 5;
        float a0 = 0.f, a1 = 0.f, a2 = 0.f, a3 = 0.f;
        #pragma unroll 4
        for (int d = 0; d < DHH; d += 4) {
            float4 a  = *(const float4*)&simg[p][d];
            float4 b0 = *(const float4*)&stit[tg     ][d];
            float4 b1 = *(const float4*)&stit[tg +  5][d];
            float4 b2 = *(const float4*)&stit[tg + 10][d];
            float4 b3 = *(const float4*)&stit[tg + 15][d];
            a0 += a.x*b0.x + a.y*b0.y + a.z*b0.z + a.w*b0.w;
            a1 += a.x*b1.x + a.y*b1.y + a.z*b1.z + a.w*b1.w;
            a2 += a.x*b2.x + a.y*b2.y + a.z*b2.z + a.w*b2.w;
            a3 += a.x*b3.x + a.y*b3.y + a.z*b3.z + a.w*b3.w;
        }
        S[p][tg     ] = a0 * 0.125f;
        S[p][tg +  5] = a1 * 0.125f;
        S[p][tg + 10] = a2 * 0.125f;
        S[p][tg + 15] = a3 * 0.125f;
    }
    __syncthreads();

    if (tid < PP) {
        const int p = tid;
        const float sc = scale_img[h * PP + p];
        float m = -1e30f;
        #pragma unroll
        for (int t = 0; t < TT; ++t) {
            float x = (msk[t] == 0) ? -1e9f : S[p][t] * sc;
            m = fmaxf(m, x);
        }
        float sum = 0.f;
        #pragma unroll
        for (int t = 0; t < TT; ++t) {
            float x = (msk[t] == 0) ? -1e9f : S[p][t] * sc;
            float e = __expf(x - m);
            pI[p][t] = e; sum += e;
        }
        float inv = 1.f / sum;
        #pragma unroll
        for (int t = 0; t < TT; ++t) pI[p][t] *= inv;
    }
    if (tid >= 64 && tid < 64 + TT) {
        const int t = tid - 64;
        const float sc = scale_tit[h * TT + t];
        const bool dead = (msk[t] == 0);
        float m = -1e30f;
        #pragma unroll
        for (int p = 0; p < PP; ++p) {
            float x = dead ? -1e9f : S[p][t] * sc;
            m = fmaxf(m, x);
        }
        float sum = 0.f;
        #pragma unroll
        for (int p = 0; p < PP; ++p) {
            float x = dead ? -1e9f : S[p][t] * sc;
            float e = __expf(x - m);
            pT[t][p] = e; sum += e;
        }
        float inv = 1.f / sum;
        #pragma unroll
        for (int p = 0; p < PP; ++p) pT[t][p] *= inv;
    }
    __syncthreads();

    {
        float accA[5] = {0.f, 0.f, 0.f, 0.f, 0.f};
        #pragma unroll
        for (int p = 0; p < 48; p += 4) {
            float v0 = simg[p + 0][lane];
            float v1 = simg[p + 1][lane];
            float v2 = simg[p + 2][lane];
            float v3 = simg[p + 3][lane];
            #pragma unroll
            for (int j = 0; j < 5; ++j) {
                const int t = wave + j * 4;
                float4 w4 = *(const float4*)&pT[t][p];
                accA[j] += v0 * w4.x + v1 * w4.y + v2 * w4.z + v3 * w4.w;
            }
        }
        {
            float v0 = simg[48][lane];
            #pragma unroll
            for (int j = 0; j < 5; ++j)
                accA[j] += v0 * pT[wave + j * 4][48];
        }
        #pragma unroll
        for (int j = 0; j < 5; ++j) {
            const int t = wave + j * 4;
            hid[(size_t)(bl * TT + t) * DD + h * DHH + lane] = f2bf(accA[j]);
        }
    }

    {
        float accB[13] = {0.f,0.f,0.f,0.f,0.f,0.f,0.f,0.f,0.f,0.f,0.f,0.f,0.f};
        #pragma unroll
        for (int t = 0; t < TT; t += 4) {
            float v0 = stit[t + 0][lane];
            float v1 = stit[t + 1][lane];
            float v2 = stit[t + 2][lane];
            float v3 = stit[t + 3][lane];
            #pragma unroll
            for (int j = 0; j < 13; ++j) {
                const int p = wave + j * 4;
                if (p < PP) {
                    float4 w4 = *(const float4*)&pI[p][t];
                    accB[j] += v0 * w4.x + v1 * w4.y + v2 * w4.z + v3 * w4.w;
                }
            }
        }
        #pragma unroll
        for (int j = 0; j < 13; ++j) {
            const int p = wave + j * 4;
            if (p < PP)
                hid[OUT_I_ELEMS + (size_t)(bl * PP + p) * DD + h * DHH + lane] = f2bf(accB[j]);
        }
    }
}

// ---------------------------------------------------------------------------
// MFMA GEMM: C[M,N] = A[M,K](bf16) @ Bw[N,K](bf16)^T + bias[N]
// 128x128 tile, BK=32, 4 waves (2x2 of 64x64), mfma_f32_16x16x32_bf16.
//
// R2 changes:
//  * 2-phase double-buffered staging: STAGE(next) issued BEFORE ds_read+MFMA
//    of current tile; single __syncthreads per K-step (its vmcnt/lgkm drain
//    covers both the in-flight stage and the fragment reads).
//  * Bank-conflict-free LDS: slot swizzle slot = q ^ ((row>>1)&3), applied
//    both-sides (pre-swizzled GLOBAL source column, LDS dest stays linear
//    per global_load_lds requirement; read XORs the slot). 8-way -> 2-way.
//  * Staging addresses (incl. M-clamp) hoisted out of the K-loop.
// ---------------------------------------------------------------------------
template<bool GELU, bool F32OUT, bool BF16OUT>
__global__ __launch_bounds__(256) void gemm_mfma(
    const unsigned short* __restrict__ A, const unsigned short* __restrict__ Bw,
    const float* __restrict__ bias,
    float* __restrict__ Cf, unsigned short* __restrict__ Cb,
    int M, int N, int K)
{
    __shared__ unsigned short As[2][128 * 32];
    __shared__ unsigned short Bs[2][128 * 32];
    const int tid  = threadIdx.x;
    const int wave = tid >> 6;
    const int lane = tid & 63;
    const int row0 = blockIdx.y * 128;
    const int col0 = blockIdx.x * 128;
    const int m_off = (wave >> 1) * 64;
    const int n_off = (wave & 1) * 64;
    const int lane_m = lane & 15;

    // Read-side swizzled slot (lane-constant across fragments):
    // row = m_off + i*16 + lane_m -> (row>>1)&3 == (lane_m>>1)&3
    const int slot8 = (((lane >> 4) ^ ((lane_m >> 1) & 3)) * 8);

    // Staging addresses, K-invariant. li in [0,512): r = li>>2 (local row),
    // stored slot s = li&3 holds global column-group c8 = s ^ ((r>>1)&3).
    const int li0 = tid, li1 = 256 + tid;
    const int r0 = li0 >> 2, r1 = li1 >> 2;
    const int c80 = (li0 & 3) ^ ((r0 >> 1) & 3);
    const int c81 = (li1 & 3) ^ ((r1 >> 1) & 3);
    int grA0 = row0 + r0; if (grA0 >= M) grA0 = M - 1;
    int grA1 = row0 + r1; if (grA1 >= M) grA1 = M - 1;
    const unsigned short* aP0 = A  + (size_t)grA0 * K + c80 * 8;
    const unsigned short* aP1 = A  + (size_t)grA1 * K + c81 * 8;
    const unsigned short* bP0 = Bw + (size_t)(col0 + r0) * K + c80 * 8;
    const unsigned short* bP1 = Bw + (size_t)(col0 + r1) * K + c81 * 8;

    f32x4 acc[4][4] = {};

    #define STAGE(buf, k0)                                                          \
        do {                                                                        \
            __builtin_amdgcn_global_load_lds(                                       \
                (const __attribute__((address_space(1))) unsigned int*)(aP0 + (k0)),\
                (__attribute__((address_space(3))) unsigned int*)&As[buf][li0 * 8], \
                16, 0, 0);                                                          \
            __builtin_amdgcn_global_load_lds(                                       \
                (const __attribute__((address_space(1))) unsigned int*)(aP1 + (k0)),\
                (__attribute__((address_space(3))) unsigned int*)&As[buf][li1 * 8], \
                16, 0, 0);                                                          \
            __builtin_amdgcn_global_load_lds(                                       \
                (const __attribute__((address_space(1))) unsigned int*)(bP0 + (k0)),\
                (__attribute__((address_space(3))) unsigned int*)&Bs[buf][li0 * 8], \
                16, 0, 0);                                                          \
            __builtin_amdgcn_global_load_lds(                                       \
                (const __attribute__((address_space(1))) unsigned int*)(bP1 + (k0)),\
                (__attribute__((address_space(3))) unsigned int*)&Bs[buf][li1 * 8], \
                16, 0, 0);                                                          \
        } while (0)

    STAGE(0, 0);
    __syncthreads();

    const int nk = K >> 5;
    for (int t = 0; t < nk; ++t) {
        const int cur = t & 1;
        if (t + 1 < nk) STAGE(cur ^ 1, (t + 1) * 32);

        bf16x8 af[4], bfr[4];
        #pragma unroll
        for (int i = 0; i < 4; ++i) {
            af[i]  = *(const bf16x8*)&As[cur][(m_off + i * 16 + lane_m) * 32 + slot8];
            bfr[i] = *(const bf16x8*)&Bs[cur][(n_off + i * 16 + lane_m) * 32 + slot8];
        }
        #pragma unroll
        for (int i = 0; i < 4; ++i)
            #pragma unroll
            for (int j = 0; j < 4; ++j)
                acc[i][j] = __builtin_amdgcn_mfma_f32_16x16x32_bf16(af[i], bfr[j], acc[i][j], 0, 0, 0);

        __syncthreads();
    }
    #undef STAGE

    // Epilogue. C/D layout: col = lane&15, row = (lane>>4)*4 + reg
    #pragma unroll
    for (int i = 0; i < 4; ++i) {
        #pragma unroll
        for (int r = 0; r < 4; ++r) {
            const int row = row0 + m_off + i * 16 + (lane >> 4) * 4 + r;
            if (row < M) {
                #pragma unroll
                for (int j = 0; j < 4; ++j) {
                    const int col = col0 + n_off + j * 16 + lane_m;
                    float v = acc[i][j][r] + bias[col];
                    if (GELU) v = gelu_fast(v);
                    if (F32OUT)  Cf[(size_t)row * N + col] = v;
                    if (BF16OUT) Cb[(size_t)row * N + col] = f2bf(v);
                }
            }
        }
    }
}

// ---------------------------------------------------------------------------
// Residual + LayerNorm (ddof=1): out[row] += a*(x-mean)/(std+eps)+b
// ---------------------------------------------------------------------------
__global__ __launch_bounds__(256) void ln_res_kernel(
    const float* __restrict__ f2, float* __restrict__ out,
    const float* __restrict__ a, const float* __restrict__ b, int M)
{
    const int wave = threadIdx.x >> 6;
    const int lane = threadIdx.x & 63;
    const int row = blockIdx.x * 4 + wave;
    if (row >= M) return;
    const float* x = f2 + (size_t)row * DD;
    float* o = out + (size_t)row * DD;

    float xs[8];
    float s1 = 0.f, s2 = 0.f;
    #pragma unroll
    for (int i = 0; i < 8; ++i) {
        float v = x[lane + i * 64];
        xs[i] = v; s1 += v; s2 += v * v;
    }
    #pragma unroll
    for (int off = 32; off > 0; off >>= 1) {
        s1 += __shfl_xor(s1, off, 64);
        s2 += __shfl_xor(s2, off, 64);
    }
    const float mean = s1 * (1.f / 512.f);
    float var = (s2 - 512.f * mean * mean) * (1.f / 511.f);
    var = fmaxf(var, 0.f);
    const float rinv = 1.f / (sqrtf(var) + 1e-6f);
    #pragma unroll
    for (int i = 0; i < 8; ++i) {
        const int d = lane + i * 64;
        o[d] = o[d] + a[d] * (xs[i] - mean) * rinv + b[d];
    }
}

// ---------------------------------------------------------------------------
extern "C" void kernel_launch(void* const* d_in, const int* in_sizes, int n_in,
                              void* d_out, int out_size, void* d_ws, size_t ws_size,
                              hipStream_t stream) {
    const float* img       = (const float*)d_in[0];
    const float* title     = (const float*)d_in[1];
    const int*   mask      = (const int*)  d_in[2];
    const float* scale_img = (const float*)d_in[3];
    const float* scale_tit = (const float*)d_in[4];
    const float* w_proj    = (const float*)d_in[5];
    const float* b_proj    = (const float*)d_in[6];
    const float* w1_img    = (const float*)d_in[7];
    const float* b1_img    = (const float*)d_in[8];
    const float* w2_img    = (const float*)d_in[9];
    const float* b2_img    = (const float*)d_in[10];
    const float* w1_tit    = (const float*)d_in[11];
    const float* b1_tit    = (const float*)d_in[12];
    const float* w2_tit    = (const float*)d_in[13];
    const float* b2_tit    = (const float*)d_in[14];
    const float* ln_a_img  = (const float*)d_in[15];
    const float* ln_b_img  = (const float*)d_in[16];
    const float* ln_a_tit  = (const float*)d_in[17];
    const float* ln_b_tit  = (const float*)d_in[18];

    float* out = (float*)d_out;
    unsigned short* hid_bf = (unsigned short*)d_ws;                       // R0 (early)
    unsigned short* act    = (unsigned short*)d_ws;                       // R0 (late)
    unsigned short* out_bf = (unsigned short*)((char*)d_ws + R1_OFF);     // R1
    float*          f2     = (float*)((char*)d_ws + R2_OFF);              // R2
    unsigned short* wp_bf  = (unsigned short*)((char*)d_ws + R3_OFF);     // R3
    unsigned short* w1i_bf = wp_bf  + 262144;
    unsigned short* w2i_bf = w1i_bf + 1048576;
    unsigned short* w1t_bf = w2i_bf + 1048576;
    unsigned short* w2t_bf = w1t_bf + 1048576;

    // 0) weights -> bf16
    cvt_kernel<<<(262144/4 + 255)/256, 256, 0, stream>>>(w_proj, wp_bf, 262144/4);
    cvt_kernel<<<(1048576/4 + 255)/256, 256, 0, stream>>>(w1_img, w1i_bf, 1048576/4);
    cvt_kernel<<<(1048576/4 + 255)/256, 256, 0, stream>>>(w2_img, w2i_bf, 1048576/4);
    cvt_kernel<<<(1048576/4 + 255)/256, 256, 0, stream>>>(w1_tit, w1t_bf, 1048576/4);
    cvt_kernel<<<(1048576/4 + 255)/256, 256, 0, stream>>>(w2_tit, w2t_bf, 1048576/4);

    // 1) attention -> hid_bf (bf16)
    attn_kernel<<<BL * HH, 256, 0, stream>>>(img, title, mask, scale_img, scale_tit, hid_bf);

    // 2) proj over all 55200 rows: fp32 -> d_out, bf16 copy -> out_bf
    gemm_mfma<false, true, true><<<dim3(DD/128, (ROWS_A + 127)/128), 256, 0, stream>>>(
        hid_bf, wp_bf, b_proj, out, out_bf, ROWS_A, DD, DD);

    // 3) img branch (16000 rows, one chunk)
    gemm_mfma<true, false, true><<<dim3(DFF/128, (ROWS_I + 127)/128), 256, 0, stream>>>(
        out_bf, w1i_bf, b1_img, nullptr, act, ROWS_I, DFF, DD);
    gemm_mfma<false, true, false><<<dim3(DD/128, (ROWS_I + 127)/128), 256, 0, stream>>>(
        act, w2i_bf, b2_img, f2, nullptr, ROWS_I, DD, DFF);
    ln_res_kernel<<<(ROWS_I + 3)/4, 256, 0, stream>>>(f2, out, ln_a_img, ln_b_img, ROWS_I);

    // 4) tit branch (39200 rows, two chunks of 19600)
    for (int c = 0; c < 2; ++c) {
        const unsigned short* a1 = out_bf + (size_t)(ROWS_I + c * CHUNK) * DD;
        float* o1 = out + OUT_I_ELEMS + (size_t)c * CHUNK * DD;
        gemm_mfma<true, false, true><<<dim3(DFF/128, (CHUNK + 127)/128), 256, 0, stream>>>(
            a1, w1t_bf, b1_tit, nullptr, act, CHUNK, DFF, DD);
        gemm_mfma<false, true, false><<<dim3(DD/128, (CHUNK + 127)/128), 256, 0, stream>>>(
            act, w2t_bf, b2_tit, f2, nullptr, CHUNK, DD, DFF);
        ln_res_kernel<<<(CHUNK + 3)/4, 256, 0, stream>>>(f2, o1, ln_a_tit, ln_b_tit, CHUNK);
    }
}